// Round 15
// baseline (270.197 us; speedup 1.0000x reference)
//
#include <hip/hip_runtime.h>
#include <hip/hip_bf16.h>
#include <stdint.h>

#define D 128
#define BM 64
#define NB_BITS 9             // 512 nodes per bucket
#define NPB (1 << NB_BITS)
#define BCAP 10240            // max edges/bucket (mean 8163)
#define C3_EPB 4096           // edges per k_bucket block (R12/R13 best)

typedef __attribute__((ext_vector_type(8))) short bf16x8;
typedef __attribute__((ext_vector_type(4))) short short4_t;
typedef __attribute__((ext_vector_type(4))) float f32x4;
typedef unsigned int uint32;

static __device__ __forceinline__ short f2bf(float f) {
  uint32_t u = __builtin_bit_cast(uint32_t, f);
  u += 0x7fffu + ((u >> 16) & 1u);   // round-to-nearest-even
  return (short)(u >> 16);
}

static __device__ __forceinline__ uint32 pk2bf(float a, float b) {
  return ((uint32)(unsigned short)f2bf(b) << 16) | (uint32)(unsigned short)f2bf(a);
}

// ---------------- prep: BT1 [256][128] = [W1|Wl1]^T ; BT2cat [128][256] = [W2;Wl2]^T ; zero bcur ----

__global__ void k_prep(const float* __restrict__ W1, const float* __restrict__ Wl1,
                       const float* __restrict__ W2, const float* __restrict__ Wl2,
                       short* __restrict__ BT1, short* __restrict__ BT2,
                       int* __restrict__ bcur) {
  int idx = blockIdx.x * 256 + threadIdx.x;
  if (idx < 2 * D * D) {
    int n = idx >> 7, k = idx & (D - 1);
    float v = (n < D) ? W1[k * D + n] : Wl1[k * D + (n - D)];
    BT1[idx] = f2bf(v);
  } else if (idx < 4 * D * D) {
    int i2 = idx - 2 * D * D;            // BT2cat: n = out col (0..127), k = 0..255
    int n = i2 >> 8, k = i2 & 255;
    float v = (k < D) ? W2[k * D + n] : Wl2[(k - D) * D + n];
    BT2[i2] = f2bf(v);
  } else if (idx < 4 * D * D + 256) {
    bcur[idx - 4 * D * D] = 0;
  }
}

// ---------------- fused front-end, INTERLEAVED roles: every `stride`-th block buckets edges,
// the rest run layer-1 GEMM. Spreads bucket blocks across time/CUs to de-burst the
// bcur reserve atomics and the rec scatter. Bucket body = R13 (per-wave hist, 8B rec).

__global__ __launch_bounds__(256) void k_b1(const int* __restrict__ src,
                                            const int* __restrict__ dst,
                                            const float* __restrict__ wgt,
                                            int* __restrict__ bcur,
                                            int2* __restrict__ rec,
                                            int E, int nb, int bblocks, int stride,
                                            const float* __restrict__ A,
                                            const short* __restrict__ BT,
                                            const float* __restrict__ bias,
                                            unsigned short* __restrict__ support,
                                            unsigned short* __restrict__ initp, int M) {
  __shared__ char smraw[BM * D * 2];             // 16 KB union
  const int t = threadIdx.x;
  const int bi = blockIdx.x;
  const bool isBucket = (bi % stride == 0) && (bi / stride < bblocks);

  if (isBucket) {
    // ---------- bucket pass ----------
    int* lh = (int*)smraw;                       // [4][256] per-wave hist/cursors, 4 KB
    const int wv = t >> 6;
    const int e0 = (bi / stride) * C3_EPB;
    for (int i = t; i < 4 * 256; i += 256) lh[i] = 0;
    __syncthreads();
    for (int i = t; i < C3_EPB; i += 256) {
      int e = e0 + i;
      if (e < E) atomicAdd(&lh[wv * 256 + (dst[e] >> NB_BITS)], 1);
    }
    __syncthreads();
    if (t < nb) {
      int h0 = lh[t], h1 = lh[256 + t], h2 = lh[512 + t], h3 = lh[768 + t];
      int base = atomicAdd(&bcur[t], h0 + h1 + h2 + h3);
      lh[t]       = base;                        // wave 0 cursor
      lh[256 + t] = base + h0;                   // wave 1 cursor
      lh[512 + t] = base + h0 + h1;
      lh[768 + t] = base + h0 + h1 + h2;
    }
    __syncthreads();
    for (int i = t; i < C3_EPB; i += 256) {
      int e = e0 + i;
      if (e < E) {
        int d = dst[e];
        int b = d >> NB_BITS;
        int r = atomicAdd(&lh[wv * 256 + b], 1); // global slot (base included)
        if (r >= BCAP) r = BCAP - 1;             // defensive clamp
        rec[(size_t)b * BCAP + r] =
            make_int2(((d & (NPB - 1)) << 17) | src[e],
                      __builtin_bit_cast(int, wgt[e]));
      }
    }
    return;
  }

  // ---------- layer-1 GEMM (verbatim) ----------
  short* As = (short*)smraw;                     // 16 KB, XOR-swizzled
  const int nbk_before = min((bi + stride - 1) / stride, bblocks);
  const int m0 = (bi - nbk_before) * BM;
  const int l = t & 63;
  const int w = t >> 6;
  const int lm = l & 15;
  const int lg = l >> 4;
  const bool full = (m0 + BM <= M);

  // issue A loads first (HBM long pole), clamped indices
  float4 aregf[8];
#pragma unroll
  for (int i = 0; i < 8; ++i) {
    int id = t + i * 256;                        // 0..2047
    int row = id >> 5, c4 = id & 31;
    int gr = m0 + row; if (gr >= M) gr = M - 1;
    aregf[i] = *(const float4*)(A + (size_t)gr * D + c4 * 4);
  }

  // B fragments (L2-hot 64KB)
  bf16x8 bfrag[4][4];
  const int colbase = w * 64 + lm;
#pragma unroll
  for (int cf = 0; cf < 4; ++cf) {
    const short* p = BT + (colbase + cf * 16) * D + lg * 8;
#pragma unroll
    for (int ks = 0; ks < 4; ++ks) bfrag[cf][ks] = *(const bf16x8*)(p + ks * 32);
  }

  // convert + LDS write (swizzled: short index ^= (row&7)<<3)
#pragma unroll
  for (int i = 0; i < 8; ++i) {
    int id = t + i * 256;
    int row = id >> 5, c4 = id & 31;
    float4 v = aregf[i];
    short4_t s4 = { f2bf(v.x), f2bf(v.y), f2bf(v.z), f2bf(v.w) };
    int sidx = row * D + ((c4 * 4) ^ ((row & 7) << 3));
    *(short4_t*)(As + sidx) = s4;
  }
  __syncthreads();

  f32x4 acc[4][4] = {};                          // [rf][cf], C^T frags
#pragma unroll
  for (int ks = 0; ks < 4; ++ks) {
    bf16x8 afrag[4];
    int kcol = ks * 32 + lg * 8;
#pragma unroll
    for (int rf = 0; rf < 4; ++rf) {
      int row = rf * 16 + lm;
      afrag[rf] = *(const bf16x8*)(As + row * D + (kcol ^ ((row & 7) << 3)));
    }
#pragma unroll
    for (int rf = 0; rf < 4; ++rf)
#pragma unroll
      for (int cf = 0; cf < 4; ++cf)
        acc[rf][cf] = __builtin_amdgcn_mfma_f32_16x16x32_bf16(
            bfrag[cf][ks], afrag[rf], acc[rf][cf], 0, 0, 0);   // SWAPPED -> C^T
  }

  // epilogue: waves 0,1 -> support (bf16); waves 2,3 -> h1b (bf16, +bias)
  const bool isInit = (w >= 2);
  const int wcol = (w & 1) * 64;

  if (!isInit) {
#pragma unroll
    for (int rf = 0; rf < 4; ++rf) {
      int m = m0 + rf * 16 + lm;
#pragma unroll
      for (int cf = 0; cf < 4; ++cf) {
        int nb2 = wcol + cf * 16 + lg * 4;
        f32x4 a = acc[rf][cf];
        uint2 pk = make_uint2(pk2bf(a[0], a[1]), pk2bf(a[2], a[3]));
        if (full || m < M)
          *(uint2*)((uint32*)support + (size_t)m * 64 + (nb2 >> 1)) = pk;
      }
    }
  } else {
    float4 bv4[4];
#pragma unroll
    for (int cf = 0; cf < 4; ++cf)
      bv4[cf] = *(const float4*)(bias + wcol + cf * 16 + lg * 4);
#pragma unroll
    for (int rf = 0; rf < 4; ++rf) {
      int m = m0 + rf * 16 + lm;
      bool ok = full || m < M;
#pragma unroll
      for (int cf = 0; cf < 4; ++cf) {
        int nb2 = wcol + cf * 16 + lg * 4;
        f32x4 a = acc[rf][cf];
        if (ok) {
          uint2 pk = make_uint2(pk2bf(a[0] + bv4[cf].x, a[1] + bv4[cf].y),
                                pk2bf(a[2] + bv4[cf].z, a[3] + bv4[cf].w));
          *(uint2*)((uint32*)initp + (size_t)m * 64 + (nb2 >> 1)) = pk;
        }
      }
    }
  }
}

// ---------------- pass 2: per-bucket LDS counting sort -> off[] + pairs[] ----------------

__global__ __launch_bounds__(256) void k_sort(const int2* __restrict__ rec,
                                              const int* __restrict__ bcur,
                                              int* __restrict__ off,
                                              int2* __restrict__ pairs,
                                              int N, int nb) {
  __shared__ int bc[256];
  __shared__ int psum[256];
  __shared__ int lofs[NPB];
  const int t = threadIdx.x;
  const int b = blockIdx.x;

  // scan bucket counts (redundant per block; 256-wide Hillis-Steele)
  int mycnt = (t < nb) ? min(bcur[t], BCAP) : 0;
  bc[t] = mycnt;
  __syncthreads();
  for (int dd = 1; dd < 256; dd <<= 1) {
    int a = (t >= dd) ? bc[t - dd] : 0;
    __syncthreads();
    bc[t] += a;
    __syncthreads();
  }
  const int cntb = min(bcur[b], BCAP);
  const int ebase = bc[b] - cntb;
  const int total = bc[nb - 1];
  const size_t rbase = (size_t)b * BCAP;
  const int n0 = b << NB_BITS;
  const int nn = min(NPB, N - n0);

  // local histogram over the bucket's nodes
  for (int i = t; i < NPB; i += 256) lofs[i] = 0;
  __syncthreads();
  for (int i = t; i < cntb; i += 256)
    atomicAdd(&lofs[(rec[rbase + i].x >> 17) & (NPB - 1)], 1);
  __syncthreads();

  // exclusive scan of 512 counts: 2/thread + 256-wide scan of partials
  int v0 = lofs[2 * t], v1 = lofs[2 * t + 1];
  int sum = v0 + v1;
  psum[t] = sum;
  __syncthreads();
  for (int dd = 1; dd < 256; dd <<= 1) {
    int a = (t >= dd) ? psum[t - dd] : 0;
    __syncthreads();
    psum[t] += a;
    __syncthreads();
  }
  int run = psum[t] - sum;
  lofs[2 * t] = run;
  lofs[2 * t + 1] = run + v0;
  __syncthreads();

  // emit per-node offsets
  for (int i = t; i < nn; i += 256) off[n0 + i] = ebase + lofs[i];
  if (b == nb - 1 && t == 0) off[N] = total;
  __syncthreads();                      // off-emit must finish before lofs is mutated

  // scatter into final sorted order (lofs doubles as cursor array)
  for (int i = t; i < cntb; i += 256) {
    int2 rr = rec[rbase + i];
    int r = atomicAdd(&lofs[(rr.x >> 17) & (NPB - 1)], 1);
    pairs[ebase + r] = make_int2(rr.x & 0x1FFFF, rr.y);
  }
}

// ---------------- aggregation (depth-8): MODE 0: io += agg (bf16 RMW); MODE 2: io = agg ----------------

template<int MODE>
__global__ __launch_bounds__(256) void k_agg(const uint32* __restrict__ sup,
                                             const int* __restrict__ off,
                                             const int2* __restrict__ pairs,
                                             uint32* __restrict__ iop, int N) {
  int node = blockIdx.x * 4 + (threadIdx.x >> 6);
  if (node >= N) return;
  const int l = threadIdx.x & 63;
  const int beg = __builtin_amdgcn_readfirstlane(off[node]);
  const int end = __builtin_amdgcn_readfirstlane(off[node + 1]);
  float ax = 0.f, ay = 0.f;
  const int nbt = (end - beg + 7) >> 3;

  if (nbt > 0) {
    int pr[8], pw[8];
#pragma unroll
    for (int i = 0; i < 8; ++i) {
      int jj = beg + i;
      int jc = jj < end ? jj : beg;
      int2 tt = pairs[jc];
      pr[i] = __builtin_amdgcn_readfirstlane(tt.x);
      pw[i] = __builtin_amdgcn_readfirstlane(jj < end ? tt.y : 0);
    }
    int j = beg + 8;
    for (int b = 1; b < nbt; ++b, j += 8) {
      int nr[8], nw[8];
#pragma unroll
      for (int i = 0; i < 8; ++i) {              // prefetch next batch (scalar)
        int jj = j + i;
        int jc = jj < end ? jj : beg;
        int2 tt = pairs[jc];
        nr[i] = __builtin_amdgcn_readfirstlane(tt.x);
        nw[i] = __builtin_amdgcn_readfirstlane(jj < end ? tt.y : 0);
      }
      uint32 v[8];
#pragma unroll
      for (int i = 0; i < 8; ++i) v[i] = sup[(size_t)(uint32)pr[i] * 64 + l];
#pragma unroll
      for (int i = 0; i < 8; ++i) {
        float w = __builtin_bit_cast(float, pw[i]);
        ax = fmaf(__builtin_bit_cast(float, v[i] << 16), w, ax);
        ay = fmaf(__builtin_bit_cast(float, v[i] & 0xffff0000u), w, ay);
      }
#pragma unroll
      for (int i = 0; i < 8; ++i) { pr[i] = nr[i]; pw[i] = nw[i]; }
    }
    uint32 v[8];
#pragma unroll
    for (int i = 0; i < 8; ++i) v[i] = sup[(size_t)(uint32)pr[i] * 64 + l];
#pragma unroll
    for (int i = 0; i < 8; ++i) {
      float w = __builtin_bit_cast(float, pw[i]);
      ax = fmaf(__builtin_bit_cast(float, v[i] << 16), w, ax);
      ay = fmaf(__builtin_bit_cast(float, v[i] & 0xffff0000u), w, ay);
    }
  }

  size_t o = (size_t)node * 64 + l;
  if (MODE == 0) {
    uint32 cur = iop[o];
    float vx = __builtin_bit_cast(float, cur << 16) + ax;
    float vy = __builtin_bit_cast(float, cur & 0xffff0000u) + ay;
    iop[o] = pk2bf(vx, vy);
  } else {
    iop[o] = pk2bf(ax, ay);
  }
}

// ---------------- layer-2 GEMM (K=256): out = (resid + [aggb|h1b]@BT2cat^T + b2)*0.5 ----------------

__global__ __launch_bounds__(256) void k_gemm2(const uint32* __restrict__ aggb,
                                               const uint32* __restrict__ h1b,
                                               const short* __restrict__ BT,
                                               const float* __restrict__ bias,
                                               const float* __restrict__ resid,
                                               float* __restrict__ out, int M) {
  __shared__ short As[BM * 256];                 // 32 KB, XOR-swizzled
  const int t = threadIdx.x;
  const int l = t & 63;
  const int w = t >> 6;
  const int lm = l & 15;
  const int lg = l >> 4;
  const int m0 = blockIdx.x * BM;
  const bool full = (m0 + BM <= M);

  // stage A = [aggb | h1b] 64x256 bf16; id 0..2047: row=id>>5, c8=id&31 (8-short chunks)
#pragma unroll
  for (int i = 0; i < 8; ++i) {
    int id = t + i * 256;
    int row = id >> 5, c8 = id & 31;
    int gr = m0 + row; if (gr >= M) gr = M - 1;
    const uint32* srcp = (c8 < 16) ? (aggb + (size_t)gr * 64 + c8 * 4)
                                   : (h1b + (size_t)gr * 64 + (c8 - 16) * 4);
    uint4 v = *(const uint4*)srcp;
    int sidx = row * 256 + ((c8 * 8) ^ ((row & 7) << 3));
    *(uint4*)(As + sidx) = v;
  }

  // B fragments: wave owns 32 out cols (2 cf), 8 ks
  bf16x8 bfrag[2][8];
  const int colbase = w * 32 + lm;
#pragma unroll
  for (int cf = 0; cf < 2; ++cf) {
    const short* p = BT + (colbase + cf * 16) * 256 + lg * 8;
#pragma unroll
    for (int ks = 0; ks < 8; ++ks) bfrag[cf][ks] = *(const bf16x8*)(p + ks * 32);
  }
  __syncthreads();

  f32x4 acc[4][2] = {};
#pragma unroll
  for (int ks = 0; ks < 8; ++ks) {
    bf16x8 afrag[4];
    int kcol = ks * 32 + lg * 8;
#pragma unroll
    for (int rf = 0; rf < 4; ++rf) {
      int row = rf * 16 + lm;
      afrag[rf] = *(const bf16x8*)(As + row * 256 + (kcol ^ ((row & 7) << 3)));
    }
#pragma unroll
    for (int rf = 0; rf < 4; ++rf)
#pragma unroll
      for (int cf = 0; cf < 2; ++cf)
        acc[rf][cf] = __builtin_amdgcn_mfma_f32_16x16x32_bf16(
            bfrag[cf][ks], afrag[rf], acc[rf][cf], 0, 0, 0);   // SWAPPED -> C^T
  }

  float4 bv4[2];
#pragma unroll
  for (int cf = 0; cf < 2; ++cf)
    bv4[cf] = *(const float4*)(bias + w * 32 + cf * 16 + lg * 4);
#pragma unroll
  for (int rf = 0; rf < 4; ++rf) {
    int m = m0 + rf * 16 + lm;
    bool ok = full || m < M;
    if (!ok) continue;
#pragma unroll
    for (int cf = 0; cf < 2; ++cf) {
      int nb = w * 32 + cf * 16 + lg * 4;
      f32x4 a = acc[rf][cf];
      float4 xr = *(const float4*)(resid + (size_t)m * D + nb);
      float4 v;
      v.x = (a[0] + bv4[cf].x + xr.x) * 0.5f;
      v.y = (a[1] + bv4[cf].y + xr.y) * 0.5f;
      v.z = (a[2] + bv4[cf].z + xr.z) * 0.5f;
      v.w = (a[3] + bv4[cf].w + xr.w) * 0.5f;
      *(float4*)(out + (size_t)m * D + nb) = v;
    }
  }
}

// ---------------- launch ----------------

extern "C" void kernel_launch(void* const* d_in, const int* in_sizes, int n_in,
                              void* d_out, int out_size, void* d_ws, size_t ws_size,
                              hipStream_t stream) {
  const float* x   = (const float*)d_in[0];
  const int*   ei  = (const int*)d_in[1];
  const float* ew  = (const float*)d_in[2];
  const float* W1  = (const float*)d_in[3];
  const float* Wl1 = (const float*)d_in[4];
  const float* b1  = (const float*)d_in[5];
  const float* W2  = (const float*)d_in[6];
  const float* Wl2 = (const float*)d_in[7];
  const float* b2  = (const float*)d_in[8];
  float* out = (float*)d_out;

  const int N = in_sizes[0] / D;
  const int E = in_sizes[1] / 2;
  const int* src = ei;
  const int* dst = ei + E;
  const int nbuck = (N + NPB - 1) >> NB_BITS;           // 196

  // workspace layout (~96 MB; rec slot kept at 31.4 MB so aggb alias still fits)
  uint32* sup = (uint32*)d_ws;                   // N*64 u32 (bf16 support1, 25.6 MB)
  uint32* h1b = sup + (size_t)N * 64;            // N*64 u32 (bf16 h1, 25.6 MB)
  short* BT1  = (short*)(h1b + (size_t)N * 64);  // 64 KB
  short* BT2  = BT1 + 2 * D * D;                 // 64 KB (BT2cat [128][256])
  int* bcur   = (int*)(BT2 + 2 * D * D);         // 256 ints
  int* off    = bcur + 256;                      // N+4 ints
  int2* pairs = (int2*)(off + (N + 4));          // E int2 (12.8 MB)
  int2* rec   = (int2*)(pairs + E);              // nbuck*BCAP int2 (16 MB used of 31.4 MB slot)
  uint32* aggb = (uint32*)rec;                   // ALIAS: N*64 u32 (25.6 MB) — rec dead after k_sort

  // weight prep + bcur zero (one launch)
  k_prep<<<(4 * D * D + 256 + 255) / 256, 256, 0, stream>>>(W1, Wl1, W2, Wl2, BT1, BT2, bcur);

  const int bblocks = (E + C3_EPB - 1) / C3_EPB;        // 391
  const int mblocks = (N + BM - 1) / BM;                // 1563
  const int ablocks = (N + 3) / 4;
  const int stride  = (bblocks + mblocks) / bblocks;    // 4 -> every 4th..5th block buckets
  const int stride_c = stride < 1 ? 1 : stride;

  // fused front-end, interleaved: sup = bf16(x@W1) ; h1b = bf16(x@Wloop1 + b1) ; rec bucketed
  k_b1<<<bblocks + mblocks, 256, 0, stream>>>(src, dst, ew, bcur, rec, E, nbuck, bblocks, stride_c,
                                              x, BT1, b1,
                                              (unsigned short*)sup, (unsigned short*)h1b, N);

  // CSR finalize
  k_sort<<<nbuck, 256, 0, stream>>>(rec, bcur, off, pairs, N, nbuck);

  // layer 1 aggregate: h1b += A@sup
  k_agg<0><<<ablocks, 256, 0, stream>>>(sup, off, pairs, h1b, N);

  // layer 2 (linearity): aggb = bf16(A@h1) ; out = (x + aggb@W2 + h1b@Wloop2 + b2)*0.5
  k_agg<2><<<ablocks, 256, 0, stream>>>(h1b, off, pairs, aggb, N);
  k_gemm2<<<mblocks, 256, 0, stream>>>(aggb, h1b, BT2, b2, x, out, N);
}

// Round 16
// 236.340 us; speedup vs baseline: 1.1433x; 1.1433x over previous
//
#include <hip/hip_runtime.h>
#include <hip/hip_bf16.h>
#include <stdint.h>

#define D 128
#define BM 64
#define NB_BITS 9             // 512 nodes per bucket
#define NPB (1 << NB_BITS)
#define BCAP 10240            // max edges/bucket (mean 8163)
#define C3_EPB 4096           // edges per k_bucket block

typedef __attribute__((ext_vector_type(8))) short bf16x8;
typedef __attribute__((ext_vector_type(4))) short short4_t;
typedef __attribute__((ext_vector_type(4))) float f32x4;
typedef unsigned int uint32;

static __device__ __forceinline__ short f2bf(float f) {
  uint32_t u = __builtin_bit_cast(uint32_t, f);
  u += 0x7fffu + ((u >> 16) & 1u);   // round-to-nearest-even
  return (short)(u >> 16);
}

static __device__ __forceinline__ uint32 pk2bf(float a, float b) {
  return ((uint32)(unsigned short)f2bf(b) << 16) | (uint32)(unsigned short)f2bf(a);
}

// ---------------- prep: BT1 [256][128] = [W1|Wl1]^T ; BT2cat [128][256] = [W2;Wl2]^T ; zero bcur ----

__global__ void k_prep(const float* __restrict__ W1, const float* __restrict__ Wl1,
                       const float* __restrict__ W2, const float* __restrict__ Wl2,
                       short* __restrict__ BT1, short* __restrict__ BT2,
                       int* __restrict__ bcur) {
  int idx = blockIdx.x * 256 + threadIdx.x;
  if (idx < 2 * D * D) {
    int n = idx >> 7, k = idx & (D - 1);
    float v = (n < D) ? W1[k * D + n] : Wl1[k * D + (n - D)];
    BT1[idx] = f2bf(v);
  } else if (idx < 4 * D * D) {
    int i2 = idx - 2 * D * D;            // BT2cat: n = out col (0..127), k = 0..255
    int n = i2 >> 8, k = i2 & 255;
    float v = (k < D) ? W2[k * D + n] : Wl2[(k - D) * D + n];
    BT2[i2] = f2bf(v);
  } else if (idx < 4 * D * D + 256) {
    bcur[idx - 4 * D * D] = 0;
  }
}

// ---------------- fused front-end: blocks [0,bblocks) = edge bucketing ; rest = layer-1 GEMM ----
// Bucket pass: PER-WAVE histograms + cursors, one global atomic per (block,bucket),
// 8B packed records ((dstlow9<<17)|src17, wgt).

__global__ __launch_bounds__(256) void k_b1(const int* __restrict__ src,
                                            const int* __restrict__ dst,
                                            const float* __restrict__ wgt,
                                            int* __restrict__ bcur,
                                            int2* __restrict__ rec,
                                            int E, int nb, int bblocks,
                                            const float* __restrict__ A,
                                            const short* __restrict__ BT,
                                            const float* __restrict__ bias,
                                            unsigned short* __restrict__ support,
                                            unsigned short* __restrict__ initp, int M) {
  __shared__ char smraw[BM * D * 2];             // 16 KB union
  const int t = threadIdx.x;

  if (blockIdx.x < bblocks) {
    // ---------- bucket pass ----------
    int* lh = (int*)smraw;                       // [4][256] per-wave hist/cursors, 4 KB
    const int wv = t >> 6;
    const int e0 = blockIdx.x * C3_EPB;
    for (int i = t; i < 4 * 256; i += 256) lh[i] = 0;
    __syncthreads();
    for (int i = t; i < C3_EPB; i += 256) {
      int e = e0 + i;
      if (e < E) atomicAdd(&lh[wv * 256 + (dst[e] >> NB_BITS)], 1);
    }
    __syncthreads();
    if (t < nb) {
      int h0 = lh[t], h1 = lh[256 + t], h2 = lh[512 + t], h3 = lh[768 + t];
      int base = atomicAdd(&bcur[t], h0 + h1 + h2 + h3);
      lh[t]       = base;                        // wave 0 cursor
      lh[256 + t] = base + h0;                   // wave 1 cursor
      lh[512 + t] = base + h0 + h1;
      lh[768 + t] = base + h0 + h1 + h2;
    }
    __syncthreads();
    for (int i = t; i < C3_EPB; i += 256) {
      int e = e0 + i;
      if (e < E) {
        int d = dst[e];
        int b = d >> NB_BITS;
        int r = atomicAdd(&lh[wv * 256 + b], 1); // global slot (base included)
        if (r >= BCAP) r = BCAP - 1;             // defensive clamp
        rec[(size_t)b * BCAP + r] =
            make_int2(((d & (NPB - 1)) << 17) | src[e],
                      __builtin_bit_cast(int, wgt[e]));
      }
    }
    return;
  }

  // ---------- layer-1 GEMM (verbatim) ----------
  short* As = (short*)smraw;                     // 16 KB, XOR-swizzled
  const int l = t & 63;
  const int w = t >> 6;
  const int lm = l & 15;
  const int lg = l >> 4;
  const int m0 = (blockIdx.x - bblocks) * BM;
  const bool full = (m0 + BM <= M);

  // issue A loads first (HBM long pole), clamped indices
  float4 aregf[8];
#pragma unroll
  for (int i = 0; i < 8; ++i) {
    int id = t + i * 256;                        // 0..2047
    int row = id >> 5, c4 = id & 31;
    int gr = m0 + row; if (gr >= M) gr = M - 1;
    aregf[i] = *(const float4*)(A + (size_t)gr * D + c4 * 4);
  }

  // B fragments (L2-hot 64KB)
  bf16x8 bfrag[4][4];
  const int colbase = w * 64 + lm;
#pragma unroll
  for (int cf = 0; cf < 4; ++cf) {
    const short* p = BT + (colbase + cf * 16) * D + lg * 8;
#pragma unroll
    for (int ks = 0; ks < 4; ++ks) bfrag[cf][ks] = *(const bf16x8*)(p + ks * 32);
  }

  // convert + LDS write (swizzled: short index ^= (row&7)<<3)
#pragma unroll
  for (int i = 0; i < 8; ++i) {
    int id = t + i * 256;
    int row = id >> 5, c4 = id & 31;
    float4 v = aregf[i];
    short4_t s4 = { f2bf(v.x), f2bf(v.y), f2bf(v.z), f2bf(v.w) };
    int sidx = row * D + ((c4 * 4) ^ ((row & 7) << 3));
    *(short4_t*)(As + sidx) = s4;
  }
  __syncthreads();

  f32x4 acc[4][4] = {};                          // [rf][cf], C^T frags
#pragma unroll
  for (int ks = 0; ks < 4; ++ks) {
    bf16x8 afrag[4];
    int kcol = ks * 32 + lg * 8;
#pragma unroll
    for (int rf = 0; rf < 4; ++rf) {
      int row = rf * 16 + lm;
      afrag[rf] = *(const bf16x8*)(As + row * D + (kcol ^ ((row & 7) << 3)));
    }
#pragma unroll
    for (int rf = 0; rf < 4; ++rf)
#pragma unroll
      for (int cf = 0; cf < 4; ++cf)
        acc[rf][cf] = __builtin_amdgcn_mfma_f32_16x16x32_bf16(
            bfrag[cf][ks], afrag[rf], acc[rf][cf], 0, 0, 0);   // SWAPPED -> C^T
  }

  // epilogue: waves 0,1 -> support (bf16); waves 2,3 -> h1b (bf16, +bias)
  const bool isInit = (w >= 2);
  const int wcol = (w & 1) * 64;

  if (!isInit) {
#pragma unroll
    for (int rf = 0; rf < 4; ++rf) {
      int m = m0 + rf * 16 + lm;
#pragma unroll
      for (int cf = 0; cf < 4; ++cf) {
        int nb2 = wcol + cf * 16 + lg * 4;
        f32x4 a = acc[rf][cf];
        uint2 pk = make_uint2(pk2bf(a[0], a[1]), pk2bf(a[2], a[3]));
        if (full || m < M)
          *(uint2*)((uint32*)support + (size_t)m * 64 + (nb2 >> 1)) = pk;
      }
    }
  } else {
    float4 bv4[4];
#pragma unroll
    for (int cf = 0; cf < 4; ++cf)
      bv4[cf] = *(const float4*)(bias + wcol + cf * 16 + lg * 4);
#pragma unroll
    for (int rf = 0; rf < 4; ++rf) {
      int m = m0 + rf * 16 + lm;
      bool ok = full || m < M;
#pragma unroll
      for (int cf = 0; cf < 4; ++cf) {
        int nb2 = wcol + cf * 16 + lg * 4;
        f32x4 a = acc[rf][cf];
        if (ok) {
          uint2 pk = make_uint2(pk2bf(a[0] + bv4[cf].x, a[1] + bv4[cf].y),
                                pk2bf(a[2] + bv4[cf].z, a[3] + bv4[cf].w));
          *(uint2*)((uint32*)initp + (size_t)m * 64 + (nb2 >> 1)) = pk;
        }
      }
    }
  }
}

// ---------------- pass 2: per-bucket LDS counting sort -> off[] + pairs[] ----------------

__global__ __launch_bounds__(256) void k_sort(const int2* __restrict__ rec,
                                              const int* __restrict__ bcur,
                                              int* __restrict__ off,
                                              int2* __restrict__ pairs,
                                              int N, int nb) {
  __shared__ int bc[256];
  __shared__ int psum[256];
  __shared__ int lofs[NPB];
  const int t = threadIdx.x;
  const int b = blockIdx.x;

  // scan bucket counts (redundant per block; 256-wide Hillis-Steele)
  int mycnt = (t < nb) ? min(bcur[t], BCAP) : 0;
  bc[t] = mycnt;
  __syncthreads();
  for (int dd = 1; dd < 256; dd <<= 1) {
    int a = (t >= dd) ? bc[t - dd] : 0;
    __syncthreads();
    bc[t] += a;
    __syncthreads();
  }
  const int cntb = min(bcur[b], BCAP);
  const int ebase = bc[b] - cntb;
  const int total = bc[nb - 1];
  const size_t rbase = (size_t)b * BCAP;
  const int n0 = b << NB_BITS;
  const int nn = min(NPB, N - n0);

  // local histogram over the bucket's nodes
  for (int i = t; i < NPB; i += 256) lofs[i] = 0;
  __syncthreads();
  for (int i = t; i < cntb; i += 256)
    atomicAdd(&lofs[(rec[rbase + i].x >> 17) & (NPB - 1)], 1);
  __syncthreads();

  // exclusive scan of 512 counts: 2/thread + 256-wide scan of partials
  int v0 = lofs[2 * t], v1 = lofs[2 * t + 1];
  int sum = v0 + v1;
  psum[t] = sum;
  __syncthreads();
  for (int dd = 1; dd < 256; dd <<= 1) {
    int a = (t >= dd) ? psum[t - dd] : 0;
    __syncthreads();
    psum[t] += a;
    __syncthreads();
  }
  int run = psum[t] - sum;
  lofs[2 * t] = run;
  lofs[2 * t + 1] = run + v0;
  __syncthreads();

  // emit per-node offsets
  for (int i = t; i < nn; i += 256) off[n0 + i] = ebase + lofs[i];
  if (b == nb - 1 && t == 0) off[N] = total;
  __syncthreads();                      // off-emit must finish before lofs is mutated

  // scatter into final sorted order (lofs doubles as cursor array)
  for (int i = t; i < cntb; i += 256) {
    int2 rr = rec[rbase + i];
    int r = atomicAdd(&lofs[(rr.x >> 17) & (NPB - 1)], 1);
    pairs[ebase + r] = make_int2(rr.x & 0x1FFFF, rr.y);
  }
}

// ---------------- aggregation (depth-8): MODE 0: io += agg (bf16 RMW); MODE 2: io = agg ----------------

template<int MODE>
__global__ __launch_bounds__(256) void k_agg(const uint32* __restrict__ sup,
                                             const int* __restrict__ off,
                                             const int2* __restrict__ pairs,
                                             uint32* __restrict__ iop, int N) {
  int node = blockIdx.x * 4 + (threadIdx.x >> 6);
  if (node >= N) return;
  const int l = threadIdx.x & 63;
  const int beg = __builtin_amdgcn_readfirstlane(off[node]);
  const int end = __builtin_amdgcn_readfirstlane(off[node + 1]);
  float ax = 0.f, ay = 0.f;
  const int nbt = (end - beg + 7) >> 3;

  if (nbt > 0) {
    int pr[8], pw[8];
#pragma unroll
    for (int i = 0; i < 8; ++i) {
      int jj = beg + i;
      int jc = jj < end ? jj : beg;
      int2 tt = pairs[jc];
      pr[i] = __builtin_amdgcn_readfirstlane(tt.x);
      pw[i] = __builtin_amdgcn_readfirstlane(jj < end ? tt.y : 0);
    }
    int j = beg + 8;
    for (int b = 1; b < nbt; ++b, j += 8) {
      int nr[8], nw[8];
#pragma unroll
      for (int i = 0; i < 8; ++i) {              // prefetch next batch (scalar)
        int jj = j + i;
        int jc = jj < end ? jj : beg;
        int2 tt = pairs[jc];
        nr[i] = __builtin_amdgcn_readfirstlane(tt.x);
        nw[i] = __builtin_amdgcn_readfirstlane(jj < end ? tt.y : 0);
      }
      uint32 v[8];
#pragma unroll
      for (int i = 0; i < 8; ++i) v[i] = sup[(size_t)(uint32)pr[i] * 64 + l];
#pragma unroll
      for (int i = 0; i < 8; ++i) {
        float w = __builtin_bit_cast(float, pw[i]);
        ax = fmaf(__builtin_bit_cast(float, v[i] << 16), w, ax);
        ay = fmaf(__builtin_bit_cast(float, v[i] & 0xffff0000u), w, ay);
      }
#pragma unroll
      for (int i = 0; i < 8; ++i) { pr[i] = nr[i]; pw[i] = nw[i]; }
    }
    uint32 v[8];
#pragma unroll
    for (int i = 0; i < 8; ++i) v[i] = sup[(size_t)(uint32)pr[i] * 64 + l];
#pragma unroll
    for (int i = 0; i < 8; ++i) {
      float w = __builtin_bit_cast(float, pw[i]);
      ax = fmaf(__builtin_bit_cast(float, v[i] << 16), w, ax);
      ay = fmaf(__builtin_bit_cast(float, v[i] & 0xffff0000u), w, ay);
    }
  }

  size_t o = (size_t)node * 64 + l;
  if (MODE == 0) {
    uint32 cur = iop[o];
    float vx = __builtin_bit_cast(float, cur << 16) + ax;
    float vy = __builtin_bit_cast(float, cur & 0xffff0000u) + ay;
    iop[o] = pk2bf(vx, vy);
  } else {
    iop[o] = pk2bf(ax, ay);
  }
}

// ---------------- layer-2 GEMM (K=256): out = (resid + [aggb|h1b]@BT2cat^T + b2)*0.5 ----------------

__global__ __launch_bounds__(256) void k_gemm2(const uint32* __restrict__ aggb,
                                               const uint32* __restrict__ h1b,
                                               const short* __restrict__ BT,
                                               const float* __restrict__ bias,
                                               const float* __restrict__ resid,
                                               float* __restrict__ out, int M) {
  __shared__ short As[BM * 256];                 // 32 KB, XOR-swizzled
  const int t = threadIdx.x;
  const int l = t & 63;
  const int w = t >> 6;
  const int lm = l & 15;
  const int lg = l >> 4;
  const int m0 = blockIdx.x * BM;
  const bool full = (m0 + BM <= M);

  // stage A = [aggb | h1b] 64x256 bf16; id 0..2047: row=id>>5, c8=id&31 (8-short chunks)
#pragma unroll
  for (int i = 0; i < 8; ++i) {
    int id = t + i * 256;
    int row = id >> 5, c8 = id & 31;
    int gr = m0 + row; if (gr >= M) gr = M - 1;
    const uint32* srcp = (c8 < 16) ? (aggb + (size_t)gr * 64 + c8 * 4)
                                   : (h1b + (size_t)gr * 64 + (c8 - 16) * 4);
    uint4 v = *(const uint4*)srcp;
    int sidx = row * 256 + ((c8 * 8) ^ ((row & 7) << 3));
    *(uint4*)(As + sidx) = v;
  }

  // B fragments: wave owns 32 out cols (2 cf), 8 ks
  bf16x8 bfrag[2][8];
  const int colbase = w * 32 + lm;
#pragma unroll
  for (int cf = 0; cf < 2; ++cf) {
    const short* p = BT + (colbase + cf * 16) * 256 + lg * 8;
#pragma unroll
    for (int ks = 0; ks < 8; ++ks) bfrag[cf][ks] = *(const bf16x8*)(p + ks * 32);
  }
  __syncthreads();

  f32x4 acc[4][2] = {};
#pragma unroll
  for (int ks = 0; ks < 8; ++ks) {
    bf16x8 afrag[4];
    int kcol = ks * 32 + lg * 8;
#pragma unroll
    for (int rf = 0; rf < 4; ++rf) {
      int row = rf * 16 + lm;
      afrag[rf] = *(const bf16x8*)(As + row * 256 + (kcol ^ ((row & 7) << 3)));
    }
#pragma unroll
    for (int rf = 0; rf < 4; ++rf)
#pragma unroll
      for (int cf = 0; cf < 2; ++cf)
        acc[rf][cf] = __builtin_amdgcn_mfma_f32_16x16x32_bf16(
            bfrag[cf][ks], afrag[rf], acc[rf][cf], 0, 0, 0);   // SWAPPED -> C^T
  }

  float4 bv4[2];
#pragma unroll
  for (int cf = 0; cf < 2; ++cf)
    bv4[cf] = *(const float4*)(bias + w * 32 + cf * 16 + lg * 4);
#pragma unroll
  for (int rf = 0; rf < 4; ++rf) {
    int m = m0 + rf * 16 + lm;
    bool ok = full || m < M;
    if (!ok) continue;
#pragma unroll
    for (int cf = 0; cf < 2; ++cf) {
      int nb = w * 32 + cf * 16 + lg * 4;
      f32x4 a = acc[rf][cf];
      float4 xr = *(const float4*)(resid + (size_t)m * D + nb);
      float4 v;
      v.x = (a[0] + bv4[cf].x + xr.x) * 0.5f;
      v.y = (a[1] + bv4[cf].y + xr.y) * 0.5f;
      v.z = (a[2] + bv4[cf].z + xr.z) * 0.5f;
      v.w = (a[3] + bv4[cf].w + xr.w) * 0.5f;
      *(float4*)(out + (size_t)m * D + nb) = v;
    }
  }
}

// ---------------- launch ----------------

extern "C" void kernel_launch(void* const* d_in, const int* in_sizes, int n_in,
                              void* d_out, int out_size, void* d_ws, size_t ws_size,
                              hipStream_t stream) {
  const float* x   = (const float*)d_in[0];
  const int*   ei  = (const int*)d_in[1];
  const float* ew  = (const float*)d_in[2];
  const float* W1  = (const float*)d_in[3];
  const float* Wl1 = (const float*)d_in[4];
  const float* b1  = (const float*)d_in[5];
  const float* W2  = (const float*)d_in[6];
  const float* Wl2 = (const float*)d_in[7];
  const float* b2  = (const float*)d_in[8];
  float* out = (float*)d_out;

  const int N = in_sizes[0] / D;
  const int E = in_sizes[1] / 2;
  const int* src = ei;
  const int* dst = ei + E;
  const int nbuck = (N + NPB - 1) >> NB_BITS;           // 196

  // workspace layout (~96 MB; rec slot kept at 31.4 MB so aggb alias still fits)
  uint32* sup = (uint32*)d_ws;                   // N*64 u32 (bf16 support1, 25.6 MB)
  uint32* h1b = sup + (size_t)N * 64;            // N*64 u32 (bf16 h1, 25.6 MB)
  short* BT1  = (short*)(h1b + (size_t)N * 64);  // 64 KB
  short* BT2  = BT1 + 2 * D * D;                 // 64 KB (BT2cat [128][256])
  int* bcur   = (int*)(BT2 + 2 * D * D);         // 256 ints
  int* off    = bcur + 256;                      // N+4 ints
  int2* pairs = (int2*)(off + (N + 4));          // E int2 (12.8 MB)
  int2* rec   = (int2*)(pairs + E);              // nbuck*BCAP int2 (16 MB used of 31.4 MB slot)
  uint32* aggb = (uint32*)rec;                   // ALIAS: N*64 u32 (25.6 MB) — rec dead after k_sort

  // weight prep + bcur zero (one launch)
  k_prep<<<(4 * D * D + 256 + 255) / 256, 256, 0, stream>>>(W1, Wl1, W2, Wl2, BT1, BT2, bcur);

  const int bblocks = (E + C3_EPB - 1) / C3_EPB;        // 391
  const int mblocks = (N + BM - 1) / BM;                // 1563
  const int ablocks = (N + 3) / 4;

  // fused front-end: edge bucketing (independent) overlapped with layer-1 GEMM
  // sup = bf16(x@W1) ; h1b = bf16(x@Wloop1 + b1)
  k_b1<<<bblocks + mblocks, 256, 0, stream>>>(src, dst, ew, bcur, rec, E, nbuck, bblocks,
                                              x, BT1, b1,
                                              (unsigned short*)sup, (unsigned short*)h1b, N);

  // CSR finalize
  k_sort<<<nbuck, 256, 0, stream>>>(rec, bcur, off, pairs, N, nbuck);

  // layer 1 aggregate: h1b += A@sup
  k_agg<0><<<ablocks, 256, 0, stream>>>(sup, off, pairs, h1b, N);

  // layer 2 (linearity): aggb = bf16(A@h1) ; out = (x + aggb@W2 + h1b@Wloop2 + b2)*0.5
  k_agg<2><<<ablocks, 256, 0, stream>>>(h1b, off, pairs, aggb, N);
  k_gemm2<<<mblocks, 256, 0, stream>>>(aggb, h1b, BT2, b2, x, out, N);
}